// Round 4
// baseline (1042.258 us; speedup 1.0000x reference)
//
#include <hip/hip_runtime.h>
#include <hip/hip_bf16.h>
#include <math.h>

#define HH 112
#define WW_ 112
#define CC 96
#define NHH 3
#define WSZ 7
#define SHIFT_ 3
#define NTOK 49
#define HDIM 32
#define WTOT 8192          // total windows = B * 16 * 16
#define MTOT 401408        // WTOT * NTOK
#define QKS 204            // qk LDS row stride (shorts): 102 dwords === 6 (mod 32) -> conflict-free kg writes
#define H1S 76             // h1 LDS row stride (shorts): 38 dwords === 6 (mod 32)
#define VTS 68             // vT row stride (shorts)

// ---- padded bf16 weight cache layout in workspace (shorts) ----
#define WQ_SZ (288 * 104)              // qkv_w rows, stride 104
#define WP_SZ (96 * 104)               // proj_w rows, stride 104
#define W1_SZ (384 * 104)              // fc1_w rows, stride 104
#define W2_SZ (6 * 96 * 72)            // fc2_w: 6 chunks of [96][72] (64 used + pad)
#define WPAD_TOT (WQ_SZ + WP_SZ + W1_SZ + W2_SZ)  // 121344
// ---- float bias/param cache offsets ----
#define BOF_QKV 0
#define BOF_PROJ 288
#define BOF_FC1 384
#define BOF_FC2 768
#define BOF_G1 864
#define BOF_B1 960
#define BOF_G2 1056
#define BOF_B2 1152
#define BIAS_TOT 1248

typedef __hip_bfloat16 bf16;
typedef __attribute__((ext_vector_type(8))) short short8;
typedef __attribute__((ext_vector_type(4))) float floatx4;

static __device__ __forceinline__ short f2bits(float v) {
  bf16 h = __float2bfloat16(v);
  short s;
  __builtin_memcpy(&s, &h, 2);
  return s;
}
static __device__ __forceinline__ float bf2f(bf16 v) { return __bfloat162float(v); }
static __device__ __forceinline__ bf16 f2bf(float v) { return __float2bfloat16(v); }

template <typename T> struct IO;
template <> struct IO<float> {
  static __device__ __forceinline__ float ld(const float* p, long i) { return p[i]; }
  static __device__ __forceinline__ void st(float* p, long i, float v) { p[i] = v; }
};
template <> struct IO<bf16> {
  static __device__ __forceinline__ float ld(const bf16* p, long i) { return bf2f(p[i]); }
  static __device__ __forceinline__ void st(bf16* p, long i, float v) { p[i] = f2bf(v); }
};

// ---------------------------------------------------------------------------
// dtype detection: flag = 1 if input is f32, 0 if bf16.
// ---------------------------------------------------------------------------
__global__ void detect_kernel(const unsigned short* __restrict__ x, int* flag) {
  __shared__ int tot;
  if (threadIdx.x == 0) tot = 0;
  __syncthreads();
  int bad = 0;
  for (int i = threadIdx.x; i < 8192; i += 256) {
    int e = (x[i] >> 7) & 0xFF;
    if (e >= 0x86) bad++;  // |value| >= 128 (or inf/nan)
  }
  atomicAdd(&tot, bad);
  __syncthreads();
  if (threadIdx.x == 0) *flag = (tot > 64) ? 1 : 0;
}

// ---------------------------------------------------------------------------
// One-time prep: convert all weights to bf16 into padded fragment-friendly
// layouts (one dwordx4 per MFMA B-frag later), biases/LN params to f32.
// ---------------------------------------------------------------------------
template <typename T>
__device__ __forceinline__ void prep_body(
    const T* qkv_w, const T* proj_w, const T* fc1_w, const T* fc2_w,
    const T* qkv_b, const T* proj_b, const T* fc1_b, const T* fc2_b,
    const T* g1, const T* b1, const T* g2, const T* b2,
    bf16* wpad, float* bias) {
  int idx = blockIdx.x * 256 + threadIdx.x;
  if (idx < WQ_SZ) {
    int r = idx / 104, c = idx % 104;
    wpad[idx] = (c < CC) ? f2bf(IO<T>::ld(qkv_w, (long)r * CC + c)) : f2bf(0.f);
  } else if (idx < WQ_SZ + WP_SZ) {
    int j = idx - WQ_SZ;
    int r = j / 104, c = j % 104;
    wpad[idx] = (c < CC) ? f2bf(IO<T>::ld(proj_w, (long)r * CC + c)) : f2bf(0.f);
  } else if (idx < WQ_SZ + WP_SZ + W1_SZ) {
    int j = idx - (WQ_SZ + WP_SZ);
    int r = j / 104, c = j % 104;
    wpad[idx] = (c < CC) ? f2bf(IO<T>::ld(fc1_w, (long)r * CC + c)) : f2bf(0.f);
  } else if (idx < WPAD_TOT) {
    int j = idx - (WQ_SZ + WP_SZ + W1_SZ);
    int ch = j / (96 * 72), rem = j % (96 * 72);
    int r = rem / 72, c = rem % 72;
    wpad[idx] = (c < 64) ? f2bf(IO<T>::ld(fc2_w, (long)r * (4 * CC) + ch * 64 + c))
                         : f2bf(0.f);
  } else if (idx < WPAD_TOT + BIAS_TOT) {
    int j = idx - WPAD_TOT;
    float v;
    if (j < 288) v = IO<T>::ld(qkv_b, j);
    else if (j < 384) v = IO<T>::ld(proj_b, j - 288);
    else if (j < 768) v = IO<T>::ld(fc1_b, j - 384);
    else if (j < 864) v = IO<T>::ld(fc2_b, j - 768);
    else if (j < 960) v = IO<T>::ld(g1, j - 864);
    else if (j < 1056) v = IO<T>::ld(b1, j - 960);
    else if (j < 1152) v = IO<T>::ld(g2, j - 1056);
    else v = IO<T>::ld(b2, j - 1152);
    bias[j] = v;
  }
}
__global__ __launch_bounds__(256) void prep_kernel(
    const int* __restrict__ flag, const void* qkv_w, const void* proj_w,
    const void* fc1_w, const void* fc2_w, const void* qkv_b, const void* proj_b,
    const void* fc1_b, const void* fc2_b, const void* g1, const void* b1,
    const void* g2, const void* b2, bf16* __restrict__ wpad,
    float* __restrict__ bias) {
  if (*flag)
    prep_body<float>((const float*)qkv_w, (const float*)proj_w, (const float*)fc1_w,
                     (const float*)fc2_w, (const float*)qkv_b, (const float*)proj_b,
                     (const float*)fc1_b, (const float*)fc2_b, (const float*)g1,
                     (const float*)b1, (const float*)g2, (const float*)b2, wpad, bias);
  else
    prep_body<bf16>((const bf16*)qkv_w, (const bf16*)proj_w, (const bf16*)fc1_w,
                    (const bf16*)fc2_w, (const bf16*)qkv_b, (const bf16*)proj_b,
                    (const bf16*)fc1_b, (const bf16*)fc2_b, (const bf16*)g1,
                    (const bf16*)b1, (const bf16*)g2, (const bf16*)b2, wpad, bias);
}

// ---------------------------------------------------------------------------
// Combined bias+mask table: comb[wi][h][m][n] (bf16)
// ---------------------------------------------------------------------------
template <typename T>
__device__ __forceinline__ void combine_body(const T* mask, const int* rel,
                                             const T* bt, bf16* comb) {
  long idx = (long)blockIdx.x * 256 + threadIdx.x;  // [wi][h][2401]
  long rem = idx % 7203;
  long wi = idx / 7203;
  int h = (int)(rem / 2401);
  int n2 = (int)(rem % 2401);
  float v = IO<T>::ld(bt, (long)rel[n2] * NHH + h) + IO<T>::ld(mask, wi * 2401 + n2);
  comb[idx] = f2bf(v);
}
__global__ __launch_bounds__(256) void combine_kernel(
    const int* __restrict__ flag, const void* mask, const int* __restrict__ rel,
    const void* bt, bf16* __restrict__ comb) {
  if (*flag)
    combine_body<float>((const float*)mask, rel, (const float*)bt, comb);
  else
    combine_body<bf16>((const bf16*)mask, rel, (const bf16*)bt, comb);
}

// ---------------------------------------------------------------------------
// Fused LN1 + QKV GEMM + MFMA window attention. One block per window.
// B-frags loaded directly from the prepped bf16 cache (1 dwordx4 each,
// L2-resident). LDS: qk[64][QKS] (Q 0..95 prescaled, K 96..191, P overlay),
// R[6656] (xln then vT). 39.4 KB -> 4 blocks/CU. 3 barriers total.
// ---------------------------------------------------------------------------
template <typename T>
__device__ __forceinline__ void qkv_attn_body(
    const T* x, const bf16* wq, const float* bias, const bf16* comb,
    bf16* attn_out, short* qk, short* R) {
  int win = blockIdx.x;
  int wave = threadIdx.x >> 6;
  int lane = threadIdx.x & 63;
  int col = lane & 15, kg = lane >> 4;
  // ---- LN1 + cyclic-shift gather -> xln (R region, stride 104, wave-local) ----
  {
    int r = lane >> 2;
    int seg = lane & 3;
    int n = wave * 16 + r;  // token in window (0..63)
    short* dst = R + n * 104 + seg * 24;
    if (n < NTOK) {
      int bq_ = win >> 8, wi = win & 255;
      int wh = wi >> 4, ww = wi & 15;
      int i = n / WSZ, j = n - (n / WSZ) * WSZ;
      int hs = wh * WSZ + i + SHIFT_; if (hs >= HH) hs -= HH;
      int ws = ww * WSZ + j + SHIFT_; if (ws >= WW_) ws -= WW_;
      const T* src = x + ((long)bq_ * (HH * WW_) + (long)hs * WW_ + ws) * CC + seg * 24;
      float a[24];
#pragma unroll
      for (int t = 0; t < 24; ++t) a[t] = IO<T>::ld(src, t);
      float s = 0.f;
#pragma unroll
      for (int t = 0; t < 24; ++t) s += a[t];
      s += __shfl_xor(s, 1, 64);
      s += __shfl_xor(s, 2, 64);
      float mean = s * (1.f / CC);
      float var = 0.f;
#pragma unroll
      for (int t = 0; t < 24; ++t) { float d = a[t] - mean; var += d * d; }
      var += __shfl_xor(var, 1, 64);
      var += __shfl_xor(var, 2, 64);
      float rstd = rsqrtf(var * (1.f / CC) + 1e-5f);
      const float* gg = bias + BOF_G1 + seg * 24;
      const float* bb = bias + BOF_B1 + seg * 24;
#pragma unroll
      for (int t = 0; t < 24; ++t)
        dst[t] = f2bits((a[t] - mean) * rstd * gg[t] + bb[t]);
    } else {
#pragma unroll
      for (int t = 0; t < 24; ++t) dst[t] = 0;
    }
  }
  // af reads only this wave's xln rows -> in-wave lgkmcnt ordering, no barrier.
  short8 af[3];
#pragma unroll
  for (int kc = 0; kc < 3; ++kc)
    af[kc] = *(const short8*)(R + (wave * 16 + col) * 104 + kc * 32 + kg * 8);
  const float scale = 0.17677669529663687f;  // 1/sqrt(32)
  // ---- Phase 1a: Q,K tiles (nc 0..11); one scheduling region, compiler
  //      pipelines the 36 dwordx4 weight loads against 36 MFMA ----
#pragma unroll
  for (int nc = 0; nc < 12; ++nc) {
    floatx4 acc = {0.f, 0.f, 0.f, 0.f};
#pragma unroll
    for (int kc = 0; kc < 3; ++kc) {
      short8 bfr = *(const short8*)(wq + (nc * 16 + col) * 104 + kc * 32 + kg * 8);
      acc = __builtin_amdgcn_mfma_f32_16x16x32_bf16(af[kc], bfr, acc, 0, 0, 0);
    }
    int cc = nc * 16 + col;
    float bb = bias[BOF_QKV + cc];
    float m = (nc < 6) ? scale : 1.f;  // prescale Q
#pragma unroll
    for (int r = 0; r < 4; ++r)
      qk[(wave * 16 + kg * 4 + r) * QKS + cc] = f2bits((acc[r] + bb) * m);
  }
  __syncthreads();  // all waves' af consumed -> xln region reusable as vT
  // ---- Phase 1b: V tiles (nc 12..17) -> transposed vT[d][token] in R ----
#pragma unroll
  for (int nc = 12; nc < 18; ++nc) {
    floatx4 acc = {0.f, 0.f, 0.f, 0.f};
#pragma unroll
    for (int kc = 0; kc < 3; ++kc) {
      short8 bfr = *(const short8*)(wq + (nc * 16 + col) * 104 + kc * 32 + kg * 8);
      acc = __builtin_amdgcn_mfma_f32_16x16x32_bf16(af[kc], bfr, acc, 0, 0, 0);
    }
    int cc = nc * 16 + col;
    float bb = bias[BOF_QKV + cc];
    int d = cc - 2 * CC;
#pragma unroll
    for (int r = 0; r < 4; ++r)
      R[d * VTS + wave * 16 + kg * 4 + r] = f2bits(acc[r] + bb);
  }
  __syncthreads();  // K,V visible to all waves
  // ---- Phase 2: S = Q K^T (registers) ----
  floatx4 st[3][4];
#pragma unroll
  for (int h = 0; h < NHH; ++h) {
    short8 qa = *(const short8*)(qk + (wave * 16 + col) * QKS + h * HDIM + kg * 8);
#pragma unroll
    for (int nt = 0; nt < 4; ++nt) {
      short8 kb = *(const short8*)(qk + (nt * 16 + col) * QKS + CC + h * HDIM + kg * 8);
      floatx4 z = {0.f, 0.f, 0.f, 0.f};
      st[h][nt] = __builtin_amdgcn_mfma_f32_16x16x32_bf16(qa, kb, z, 0, 0, 0);
    }
  }
  __syncthreads();  // Q,K region dead -> P overlay safe
  // ---- Phase 3: softmax, P overlay into qk cols 0..191 (wave-local rows) ----
  const bf16* cb = comb + (long)(win & 255) * (NHH * 2401);
#pragma unroll
  for (int h = 0; h < NHH; ++h) {
#pragma unroll
    for (int r = 0; r < 4; ++r) {
      int m = wave * 16 + kg * 4 + r;
      int mc = (m < NTOK) ? m : (NTOK - 1);
      float sv[4];
      float mx = -1e30f;
#pragma unroll
      for (int nt = 0; nt < 4; ++nt) {
        int n = nt * 16 + col;
        float v = (n < NTOK)
                      ? (st[h][nt][r] + bf2f(cb[h * 2401 + mc * NTOK + n]))
                      : -1e30f;
        sv[nt] = v;
        mx = fmaxf(mx, v);
      }
#pragma unroll
      for (int msk = 1; msk < 16; msk <<= 1) mx = fmaxf(mx, __shfl_xor(mx, msk, 64));
      float sum = 0.f;
#pragma unroll
      for (int nt = 0; nt < 4; ++nt) {
        float e = __expf(sv[nt] - mx);
        sv[nt] = e;
        sum += e;
      }
#pragma unroll
      for (int msk = 1; msk < 16; msk <<= 1) sum += __shfl_xor(sum, msk, 64);
      float inv = 1.f / sum;
#pragma unroll
      for (int nt = 0; nt < 4; ++nt)
        qk[m * QKS + h * 64 + nt * 16 + col] = f2bits(sv[nt] * inv);
    }
  }
  // ---- Phase 4: O = P V (P rows + pa reads wave-local; V synced earlier) ----
#pragma unroll
  for (int h = 0; h < NHH; ++h) {
    floatx4 oa[2];
    oa[0] = (floatx4){0.f, 0.f, 0.f, 0.f};
    oa[1] = (floatx4){0.f, 0.f, 0.f, 0.f};
#pragma unroll
    for (int kc = 0; kc < 2; ++kc) {
      short8 pa = *(const short8*)(qk + (wave * 16 + col) * QKS + h * 64 + kc * 32 + kg * 8);
#pragma unroll
      for (int dt = 0; dt < 2; ++dt) {
        short8 vb = *(const short8*)(R + (h * HDIM + dt * 16 + col) * VTS + kc * 32 + kg * 8);
        oa[dt] = __builtin_amdgcn_mfma_f32_16x16x32_bf16(pa, vb, oa[dt], 0, 0, 0);
      }
    }
#pragma unroll
    for (int dt = 0; dt < 2; ++dt)
#pragma unroll
      for (int r = 0; r < 4; ++r) {
        int m = wave * 16 + kg * 4 + r;
        if (m < NTOK)
          attn_out[((long)win * NTOK + m) * CC + h * HDIM + dt * 16 + col] =
              f2bf(oa[dt][r]);
      }
  }
}
__global__ __launch_bounds__(256, 4) void qkv_attn_kernel(
    const int* __restrict__ flag, const void* x, const bf16* __restrict__ wq,
    const float* __restrict__ bias, const bf16* __restrict__ comb,
    bf16* __restrict__ attn_out) {
  __shared__ short qk[64 * QKS];
  __shared__ short R[6656];
  if (*flag)
    qkv_attn_body<float>((const float*)x, wq, bias, comb, attn_out, qk, R);
  else
    qkv_attn_body<bf16>((const bf16*)x, wq, bias, comb, attn_out, qk, R);
}

// ---------------------------------------------------------------------------
// window reverse + reverse shift index for token m (window order) -> image
// ---------------------------------------------------------------------------
static __device__ __forceinline__ long scatter_index(long m) {
  int win = (int)(m / NTOK);
  int n = (int)(m - (long)win * NTOK);
  int bq = win >> 8, wi = win & 255;
  int wh = wi >> 4, ww = wi & 15;
  int i = n / WSZ, j = n - (n / WSZ) * WSZ;
  int hf = wh * WSZ + i + SHIFT_; if (hf >= HH) hf -= HH;
  int wf = ww * WSZ + j + SHIFT_; if (wf >= WW_) wf -= WW_;
  return ((long)bq * (HH * WW_) + (long)hf * WW_ + wf) * CC;
}

// ---------------------------------------------------------------------------
// Proj GEMM (96x96, W frags direct from prepped bf16 cache) + scatter +
// shortcut add. Zero LDS, zero barriers.
// ---------------------------------------------------------------------------
template <typename T>
__device__ __forceinline__ void proj_body(const bf16* A, const bf16* wp,
                                          const float* bias, T* out,
                                          const T* res) {
  int wave = threadIdx.x >> 6;
  int lane = threadIdx.x & 63;
  int col = lane & 15;
  int kg = lane >> 4;
  long mbase = (long)blockIdx.x * 128 + wave * 32;
  short8 a0[3], a1[3];
#pragma unroll
  for (int kc = 0; kc < 3; ++kc) {
    a0[kc] = *(const short8*)(A + (mbase + col) * CC + kc * 32 + kg * 8);
    a1[kc] = *(const short8*)(A + (mbase + 16 + col) * CC + kc * 32 + kg * 8);
  }
  long dst0[4], dst1[4];
#pragma unroll
  for (int r = 0; r < 4; ++r) {
    dst0[r] = scatter_index(mbase + kg * 4 + r);
    dst1[r] = scatter_index(mbase + 16 + kg * 4 + r);
  }
#pragma unroll
  for (int nc = 0; nc < 6; ++nc) {
    floatx4 acc0 = {0.f, 0.f, 0.f, 0.f};
    floatx4 acc1 = {0.f, 0.f, 0.f, 0.f};
#pragma unroll
    for (int kc = 0; kc < 3; ++kc) {
      short8 bfr = *(const short8*)(wp + (nc * 16 + col) * 104 + kc * 32 + kg * 8);
      acc0 = __builtin_amdgcn_mfma_f32_16x16x32_bf16(a0[kc], bfr, acc0, 0, 0, 0);
      acc1 = __builtin_amdgcn_mfma_f32_16x16x32_bf16(a1[kc], bfr, acc1, 0, 0, 0);
    }
    int cc = nc * 16 + col;
    float bb = bias[BOF_PROJ + cc];
#pragma unroll
    for (int r = 0; r < 4; ++r) {
      long p0 = dst0[r] + cc;
      long p1 = dst1[r] + cc;
      IO<T>::st(out, p0, acc0[r] + bb + IO<T>::ld(res, p0));
      IO<T>::st(out, p1, acc1[r] + bb + IO<T>::ld(res, p1));
    }
  }
}
__global__ __launch_bounds__(256, 4) void proj_kernel(
    const int* __restrict__ flag, const bf16* __restrict__ A,
    const bf16* __restrict__ wp, const float* __restrict__ bias, void* out,
    const void* res) {
  if (*flag)
    proj_body<float>(A, wp, bias, (float*)out, (const float*)res);
  else
    proj_body<bf16>(A, wp, bias, (bf16*)out, (const bf16*)res);
}

// ---------------------------------------------------------------------------
// Fused LN2 + MLP. One block = 64 rows. Weight frags direct from prepped
// cache (1 dwordx4 each). h1 round-trips through the (dead) xln region, BUT
// the stride change (104 -> 76) makes h1c rows alias OTHER waves' xln rows
// (wave 3 h1c shorts [3648,4851] overlap wave 2 xln [3328,4991]): ONE barrier
// after all af loads is required before the first h1c write. (Round-3 bug.)
// LDS 13.3 KB -> 8 blocks/CU.
// ---------------------------------------------------------------------------
template <typename T>
__device__ __forceinline__ void mlp_body(const bf16* w1, const bf16* w2,
                                         const float* bias, T* xo, short* xln) {
  int wave = threadIdx.x >> 6;
  int lane = threadIdx.x & 63;
  int col = lane & 15;
  int kg = lane >> 4;
  long mbase = (long)blockIdx.x * 64;
  // ---- LN2 on x1 (= xo) -> xln (wave-local rows) ----
  {
    int r = lane >> 2;
    int seg = lane & 3;
    const T* src = xo + (mbase + wave * 16 + r) * CC + seg * 24;
    float a[24];
#pragma unroll
    for (int t = 0; t < 24; ++t) a[t] = IO<T>::ld(src, t);
    float s = 0.f;
#pragma unroll
    for (int t = 0; t < 24; ++t) s += a[t];
    s += __shfl_xor(s, 1, 64);
    s += __shfl_xor(s, 2, 64);
    float mean = s * (1.f / CC);
    float var = 0.f;
#pragma unroll
    for (int t = 0; t < 24; ++t) { float d = a[t] - mean; var += d * d; }
    var += __shfl_xor(var, 1, 64);
    var += __shfl_xor(var, 2, 64);
    float rstd = rsqrtf(var * (1.f / CC) + 1e-5f);
    const float* gg = bias + BOF_G2 + seg * 24;
    const float* bb = bias + BOF_B2 + seg * 24;
    short* dst = xln + (wave * 16 + r) * 104 + seg * 24;
#pragma unroll
    for (int t = 0; t < 24; ++t)
      dst[t] = f2bits((a[t] - mean) * rstd * gg[t] + bb[t]);
  }
  // af reads this wave's own xln rows -> in-wave ordering, no barrier needed
  short8 af[3];
#pragma unroll
  for (int kc = 0; kc < 3; ++kc)
    af[kc] = *(const short8*)(xln + (wave * 16 + col) * 104 + kc * 32 + kg * 8);
  __syncthreads();  // ALL waves' af loaded before h1c overlay (stride alias!)
  short* h1c = xln;  // xln dead now -> reuse as h1 chunk (stride H1S)
  floatx4 acc2[6];
#pragma unroll
  for (int i = 0; i < 6; ++i) acc2[i] = (floatx4){0.f, 0.f, 0.f, 0.f};
  for (int c = 0; c < 6; ++c) {
    // FC1 chunk: 4 n-tiles -> gelu -> h1c (wave-local rows)
#pragma unroll
    for (int t = 0; t < 4; ++t) {
      floatx4 acc = {0.f, 0.f, 0.f, 0.f};
#pragma unroll
      for (int kc = 0; kc < 3; ++kc) {
        short8 bfr =
            *(const short8*)(w1 + (c * 64 + t * 16 + col) * 104 + kc * 32 + kg * 8);
        acc = __builtin_amdgcn_mfma_f32_16x16x32_bf16(af[kc], bfr, acc, 0, 0, 0);
      }
      float bb = bias[BOF_FC1 + c * 64 + t * 16 + col];
#pragma unroll
      for (int r = 0; r < 4; ++r) {
        float v = acc[r] + bb;
        float ge = 0.5f * v * (1.f + erff(v * 0.70710678118654752f));
        h1c[(wave * 16 + kg * 4 + r) * H1S + t * 16 + col] = f2bits(ge);
      }
    }
    // FC2 partial (h1c rows wave-local -> in-wave ordering, no barrier)
    short8 a2[2];
#pragma unroll
    for (int kk = 0; kk < 2; ++kk)
      a2[kk] = *(const short8*)(h1c + (wave * 16 + col) * H1S + kk * 32 + kg * 8);
#pragma unroll
    for (int nc2 = 0; nc2 < 6; ++nc2) {
#pragma unroll
      for (int kk = 0; kk < 2; ++kk) {
        short8 b2f = *(const short8*)(w2 + c * (96 * 72) + (nc2 * 16 + col) * 72 +
                                      kk * 32 + kg * 8);
        acc2[nc2] = __builtin_amdgcn_mfma_f32_16x16x32_bf16(a2[kk], b2f, acc2[nc2], 0, 0, 0);
      }
    }
  }
  // ---- epilogue: + fc2_b + residual(x1), write back ----
#pragma unroll
  for (int nc2 = 0; nc2 < 6; ++nc2) {
    int cc = nc2 * 16 + col;
    float bb = bias[BOF_FC2 + cc];
#pragma unroll
    for (int r = 0; r < 4; ++r) {
      long p = (mbase + wave * 16 + kg * 4 + r) * CC + cc;
      IO<T>::st(xo, p, acc2[nc2][r] + bb + IO<T>::ld(xo, p));
    }
  }
}
__global__ __launch_bounds__(256, 8) void mlp_kernel(
    const int* __restrict__ flag, const bf16* __restrict__ w1,
    const bf16* __restrict__ w2, const float* __restrict__ bias, void* xo) {
  __shared__ short xln[64 * 104];
  if (*flag)
    mlp_body<float>(w1, w2, bias, (float*)xo, xln);
  else
    mlp_body<bf16>(w1, w2, bias, (bf16*)xo, xln);
}

// ---------------------------------------------------------------------------
extern "C" void kernel_launch(void* const* d_in, const int* in_sizes, int n_in,
                              void* d_out, int out_size, void* d_ws, size_t ws_size,
                              hipStream_t stream) {
  (void)in_sizes; (void)n_in; (void)out_size; (void)ws_size;
  char* ws = (char*)d_ws;
  bf16* bufA = (bf16*)ws;                                   // MTOT*96 bf16 = 77 MB
  size_t offComb = (size_t)MTOT * CC * 2;
  bf16* comb = (bf16*)(ws + offComb);                       // 256*3*2401 bf16 = 3.7 MB
  size_t offW = offComb + (size_t)256 * NHH * 2401 * 2;
  bf16* wpad = (bf16*)(ws + offW);                          // 237 KB padded bf16 weights
  size_t offB = offW + (size_t)WPAD_TOT * 2;
  float* bias = (float*)(ws + offB);                        // 4.9 KB f32 biases/params
  int* flag = (int*)(ws + offB + (size_t)BIAS_TOT * 4);

  detect_kernel<<<1, 256, 0, stream>>>((const unsigned short*)d_in[0], flag);
  prep_kernel<<<(WPAD_TOT + BIAS_TOT + 255) / 256, 256, 0, stream>>>(
      flag, d_in[5], d_in[7], d_in[12], d_in[14], d_in[6], d_in[8], d_in[13],
      d_in[15], d_in[3], d_in[4], d_in[10], d_in[11], wpad, bias);
  combine_kernel<<<7203, 256, 0, stream>>>(flag, d_in[1], (const int*)d_in[2],
                                           d_in[9], comb);
  // 1. LN1 + shift + QKV + attention -> bufA
  qkv_attn_kernel<<<WTOT, 256, 0, stream>>>(flag, d_in[0], wpad, bias, comb, bufA);
  // 2. proj + scatter + shortcut -> x1 parked in d_out
  proj_kernel<<<MTOT / 128, 256, 0, stream>>>(flag, bufA, wpad + WQ_SZ, bias,
                                              d_out, d_in[0]);
  // 3. LN2 + MLP + residual, in-place on d_out
  mlp_kernel<<<MTOT / 64, 256, 0, stream>>>(flag, wpad + WQ_SZ + WP_SZ,
                                            wpad + WQ_SZ + WP_SZ + W1_SZ, bias,
                                            d_out);
}

// Round 5
// 862.463 us; speedup vs baseline: 1.2085x; 1.2085x over previous
//
#include <hip/hip_runtime.h>
#include <hip/hip_bf16.h>
#include <math.h>

#define HH 112
#define WW_ 112
#define CC 96
#define NHH 3
#define WSZ 7
#define SHIFT_ 3
#define NTOK 49
#define HDIM 32
#define WTOT 8192          // total windows = B * 16 * 16
#define MTOT 401408        // WTOT * NTOK
#define QKS 204            // qk LDS row stride (shorts): 102 dwords === 6 (mod 32) -> conflict-free kg writes
#define H1S 76             // h1 LDS row stride (shorts): 38 dwords === 6 (mod 32)
#define VTS 68             // vT row stride (shorts)
#define XSS 97             // xstash row stride (floats): 97 === 1 (mod 32) -> row-spread banks

// ---- padded bf16 weight cache layout in workspace (shorts) ----
#define WQ_SZ (288 * 104)              // qkv_w rows, stride 104
#define WP_SZ (96 * 104)               // proj_w rows, stride 104
#define W1_SZ (384 * 104)              // fc1_w rows, stride 104
#define W2_SZ (6 * 96 * 72)            // fc2_w: 6 chunks of [96][72] (64 used + pad)
#define WPAD_TOT (WQ_SZ + WP_SZ + W1_SZ + W2_SZ)  // 121344
// ---- float bias/param cache offsets ----
#define BOF_QKV 0
#define BOF_PROJ 288
#define BOF_FC1 384
#define BOF_FC2 768
#define BOF_G1 864
#define BOF_B1 960
#define BOF_G2 1056
#define BOF_B2 1152
#define BIAS_TOT 1248

typedef __hip_bfloat16 bf16;
typedef __attribute__((ext_vector_type(8))) short short8;
typedef __attribute__((ext_vector_type(4))) float floatx4;

static __device__ __forceinline__ short f2bits(float v) {
  bf16 h = __float2bfloat16(v);
  short s;
  __builtin_memcpy(&s, &h, 2);
  return s;
}
static __device__ __forceinline__ float bf2f(bf16 v) { return __bfloat162float(v); }
static __device__ __forceinline__ bf16 f2bf(float v) { return __float2bfloat16(v); }

template <typename T> struct IO;
template <> struct IO<float> {
  static __device__ __forceinline__ float ld(const float* p, long i) { return p[i]; }
  static __device__ __forceinline__ void st(float* p, long i, float v) { p[i] = v; }
};
template <> struct IO<bf16> {
  static __device__ __forceinline__ float ld(const bf16* p, long i) { return bf2f(p[i]); }
  static __device__ __forceinline__ void st(bf16* p, long i, float v) { p[i] = f2bf(v); }
};

// ---------------------------------------------------------------------------
// dtype detection: flag = 1 if input is f32, 0 if bf16.
// ---------------------------------------------------------------------------
__global__ void detect_kernel(const unsigned short* __restrict__ x, int* flag) {
  __shared__ int tot;
  if (threadIdx.x == 0) tot = 0;
  __syncthreads();
  int bad = 0;
  for (int i = threadIdx.x; i < 8192; i += 256) {
    int e = (x[i] >> 7) & 0xFF;
    if (e >= 0x86) bad++;  // |value| >= 128 (or inf/nan)
  }
  atomicAdd(&tot, bad);
  __syncthreads();
  if (threadIdx.x == 0) *flag = (tot > 64) ? 1 : 0;
}

// ---------------------------------------------------------------------------
// One-time prep: convert all weights to bf16 into padded fragment-friendly
// layouts (one dwordx4 per MFMA B-frag later), biases/LN params to f32.
// ---------------------------------------------------------------------------
template <typename T>
__device__ __forceinline__ void prep_body(
    const T* qkv_w, const T* proj_w, const T* fc1_w, const T* fc2_w,
    const T* qkv_b, const T* proj_b, const T* fc1_b, const T* fc2_b,
    const T* g1, const T* b1, const T* g2, const T* b2,
    bf16* wpad, float* bias) {
  int idx = blockIdx.x * 256 + threadIdx.x;
  if (idx < WQ_SZ) {
    int r = idx / 104, c = idx % 104;
    wpad[idx] = (c < CC) ? f2bf(IO<T>::ld(qkv_w, (long)r * CC + c)) : f2bf(0.f);
  } else if (idx < WQ_SZ + WP_SZ) {
    int j = idx - WQ_SZ;
    int r = j / 104, c = j % 104;
    wpad[idx] = (c < CC) ? f2bf(IO<T>::ld(proj_w, (long)r * CC + c)) : f2bf(0.f);
  } else if (idx < WQ_SZ + WP_SZ + W1_SZ) {
    int j = idx - (WQ_SZ + WP_SZ);
    int r = j / 104, c = j % 104;
    wpad[idx] = (c < CC) ? f2bf(IO<T>::ld(fc1_w, (long)r * CC + c)) : f2bf(0.f);
  } else if (idx < WPAD_TOT) {
    int j = idx - (WQ_SZ + WP_SZ + W1_SZ);
    int ch = j / (96 * 72), rem = j % (96 * 72);
    int r = rem / 72, c = rem % 72;
    wpad[idx] = (c < 64) ? f2bf(IO<T>::ld(fc2_w, (long)r * (4 * CC) + ch * 64 + c))
                         : f2bf(0.f);
  } else if (idx < WPAD_TOT + BIAS_TOT) {
    int j = idx - WPAD_TOT;
    float v;
    if (j < 288) v = IO<T>::ld(qkv_b, j);
    else if (j < 384) v = IO<T>::ld(proj_b, j - 288);
    else if (j < 768) v = IO<T>::ld(fc1_b, j - 384);
    else if (j < 864) v = IO<T>::ld(fc2_b, j - 768);
    else if (j < 960) v = IO<T>::ld(g1, j - 864);
    else if (j < 1056) v = IO<T>::ld(b1, j - 960);
    else if (j < 1152) v = IO<T>::ld(g2, j - 1056);
    else v = IO<T>::ld(b2, j - 1152);
    bias[j] = v;
  }
}
__global__ __launch_bounds__(256) void prep_kernel(
    const int* __restrict__ flag, const void* qkv_w, const void* proj_w,
    const void* fc1_w, const void* fc2_w, const void* qkv_b, const void* proj_b,
    const void* fc1_b, const void* fc2_b, const void* g1, const void* b1,
    const void* g2, const void* b2, bf16* __restrict__ wpad,
    float* __restrict__ bias) {
  if (*flag)
    prep_body<float>((const float*)qkv_w, (const float*)proj_w, (const float*)fc1_w,
                     (const float*)fc2_w, (const float*)qkv_b, (const float*)proj_b,
                     (const float*)fc1_b, (const float*)fc2_b, (const float*)g1,
                     (const float*)b1, (const float*)g2, (const float*)b2, wpad, bias);
  else
    prep_body<bf16>((const bf16*)qkv_w, (const bf16*)proj_w, (const bf16*)fc1_w,
                    (const bf16*)fc2_w, (const bf16*)qkv_b, (const bf16*)proj_b,
                    (const bf16*)fc1_b, (const bf16*)fc2_b, (const bf16*)g1,
                    (const bf16*)b1, (const bf16*)g2, (const bf16*)b2, wpad, bias);
}

// ---------------------------------------------------------------------------
// Combined bias+mask table: comb[wi][h][m][n] (bf16)
// ---------------------------------------------------------------------------
template <typename T>
__device__ __forceinline__ void combine_body(const T* mask, const int* rel,
                                             const T* bt, bf16* comb) {
  long idx = (long)blockIdx.x * 256 + threadIdx.x;  // [wi][h][2401]
  long rem = idx % 7203;
  long wi = idx / 7203;
  int h = (int)(rem / 2401);
  int n2 = (int)(rem % 2401);
  float v = IO<T>::ld(bt, (long)rel[n2] * NHH + h) + IO<T>::ld(mask, wi * 2401 + n2);
  comb[idx] = f2bf(v);
}
__global__ __launch_bounds__(256) void combine_kernel(
    const int* __restrict__ flag, const void* mask, const int* __restrict__ rel,
    const void* bt, bf16* __restrict__ comb) {
  if (*flag)
    combine_body<float>((const float*)mask, rel, (const float*)bt, comb);
  else
    combine_body<bf16>((const bf16*)mask, rel, (const bf16*)bt, comb);
}

// ---------------------------------------------------------------------------
// Fused LN1 + QKV GEMM + MFMA window attention. One block per window.
// B-frags loaded directly from the prepped bf16 cache (1 dwordx4 each,
// L2-resident). LDS: qk[64][QKS] (Q 0..95 prescaled, K 96..191, P overlay),
// R[6656] (xln then vT). 39.4 KB -> 4 blocks/CU. 3 barriers total.
// ---------------------------------------------------------------------------
template <typename T>
__device__ __forceinline__ void qkv_attn_body(
    const T* x, const bf16* wq, const float* bias, const bf16* comb,
    bf16* attn_out, short* qk, short* R) {
  int win = blockIdx.x;
  int wave = threadIdx.x >> 6;
  int lane = threadIdx.x & 63;
  int col = lane & 15, kg = lane >> 4;
  // ---- LN1 + cyclic-shift gather -> xln (R region, stride 104, wave-local) ----
  {
    int r = lane >> 2;
    int seg = lane & 3;
    int n = wave * 16 + r;  // token in window (0..63)
    short* dst = R + n * 104 + seg * 24;
    if (n < NTOK) {
      int bq_ = win >> 8, wi = win & 255;
      int wh = wi >> 4, ww = wi & 15;
      int i = n / WSZ, j = n - (n / WSZ) * WSZ;
      int hs = wh * WSZ + i + SHIFT_; if (hs >= HH) hs -= HH;
      int ws = ww * WSZ + j + SHIFT_; if (ws >= WW_) ws -= WW_;
      const T* src = x + ((long)bq_ * (HH * WW_) + (long)hs * WW_ + ws) * CC + seg * 24;
      float a[24];
#pragma unroll
      for (int t = 0; t < 24; ++t) a[t] = IO<T>::ld(src, t);
      float s = 0.f;
#pragma unroll
      for (int t = 0; t < 24; ++t) s += a[t];
      s += __shfl_xor(s, 1, 64);
      s += __shfl_xor(s, 2, 64);
      float mean = s * (1.f / CC);
      float var = 0.f;
#pragma unroll
      for (int t = 0; t < 24; ++t) { float d = a[t] - mean; var += d * d; }
      var += __shfl_xor(var, 1, 64);
      var += __shfl_xor(var, 2, 64);
      float rstd = rsqrtf(var * (1.f / CC) + 1e-5f);
      const float* gg = bias + BOF_G1 + seg * 24;
      const float* bb = bias + BOF_B1 + seg * 24;
#pragma unroll
      for (int t = 0; t < 24; ++t)
        dst[t] = f2bits((a[t] - mean) * rstd * gg[t] + bb[t]);
    } else {
#pragma unroll
      for (int t = 0; t < 24; ++t) dst[t] = 0;
    }
  }
  // af reads only this wave's xln rows -> in-wave lgkmcnt ordering, no barrier.
  short8 af[3];
#pragma unroll
  for (int kc = 0; kc < 3; ++kc)
    af[kc] = *(const short8*)(R + (wave * 16 + col) * 104 + kc * 32 + kg * 8);
  const float scale = 0.17677669529663687f;  // 1/sqrt(32)
  // ---- Phase 1a: Q,K tiles (nc 0..11); one scheduling region, compiler
  //      pipelines the 36 dwordx4 weight loads against 36 MFMA ----
#pragma unroll
  for (int nc = 0; nc < 12; ++nc) {
    floatx4 acc = {0.f, 0.f, 0.f, 0.f};
#pragma unroll
    for (int kc = 0; kc < 3; ++kc) {
      short8 bfr = *(const short8*)(wq + (nc * 16 + col) * 104 + kc * 32 + kg * 8);
      acc = __builtin_amdgcn_mfma_f32_16x16x32_bf16(af[kc], bfr, acc, 0, 0, 0);
    }
    int cc = nc * 16 + col;
    float bb = bias[BOF_QKV + cc];
    float m = (nc < 6) ? scale : 1.f;  // prescale Q
#pragma unroll
    for (int r = 0; r < 4; ++r)
      qk[(wave * 16 + kg * 4 + r) * QKS + cc] = f2bits((acc[r] + bb) * m);
  }
  __syncthreads();  // all waves' af consumed -> xln region reusable as vT
  // ---- Phase 1b: V tiles (nc 12..17) -> transposed vT[d][token] in R ----
#pragma unroll
  for (int nc = 12; nc < 18; ++nc) {
    floatx4 acc = {0.f, 0.f, 0.f, 0.f};
#pragma unroll
    for (int kc = 0; kc < 3; ++kc) {
      short8 bfr = *(const short8*)(wq + (nc * 16 + col) * 104 + kc * 32 + kg * 8);
      acc = __builtin_amdgcn_mfma_f32_16x16x32_bf16(af[kc], bfr, acc, 0, 0, 0);
    }
    int cc = nc * 16 + col;
    float bb = bias[BOF_QKV + cc];
    int d = cc - 2 * CC;
#pragma unroll
    for (int r = 0; r < 4; ++r)
      R[d * VTS + wave * 16 + kg * 4 + r] = f2bits(acc[r] + bb);
  }
  __syncthreads();  // K,V visible to all waves
  // ---- Phase 2: S = Q K^T (registers) ----
  floatx4 st[3][4];
#pragma unroll
  for (int h = 0; h < NHH; ++h) {
    short8 qa = *(const short8*)(qk + (wave * 16 + col) * QKS + h * HDIM + kg * 8);
#pragma unroll
    for (int nt = 0; nt < 4; ++nt) {
      short8 kb = *(const short8*)(qk + (nt * 16 + col) * QKS + CC + h * HDIM + kg * 8);
      floatx4 z = {0.f, 0.f, 0.f, 0.f};
      st[h][nt] = __builtin_amdgcn_mfma_f32_16x16x32_bf16(qa, kb, z, 0, 0, 0);
    }
  }
  __syncthreads();  // Q,K region dead -> P overlay safe
  // ---- Phase 3: softmax, P overlay into qk cols 0..191 (wave-local rows) ----
  const bf16* cb = comb + (long)(win & 255) * (NHH * 2401);
#pragma unroll
  for (int h = 0; h < NHH; ++h) {
#pragma unroll
    for (int r = 0; r < 4; ++r) {
      int m = wave * 16 + kg * 4 + r;
      int mc = (m < NTOK) ? m : (NTOK - 1);
      float sv[4];
      float mx = -1e30f;
#pragma unroll
      for (int nt = 0; nt < 4; ++nt) {
        int n = nt * 16 + col;
        float v = (n < NTOK)
                      ? (st[h][nt][r] + bf2f(cb[h * 2401 + mc * NTOK + n]))
                      : -1e30f;
        sv[nt] = v;
        mx = fmaxf(mx, v);
      }
#pragma unroll
      for (int msk = 1; msk < 16; msk <<= 1) mx = fmaxf(mx, __shfl_xor(mx, msk, 64));
      float sum = 0.f;
#pragma unroll
      for (int nt = 0; nt < 4; ++nt) {
        float e = __expf(sv[nt] - mx);
        sv[nt] = e;
        sum += e;
      }
#pragma unroll
      for (int msk = 1; msk < 16; msk <<= 1) sum += __shfl_xor(sum, msk, 64);
      float inv = 1.f / sum;
#pragma unroll
      for (int nt = 0; nt < 4; ++nt)
        qk[m * QKS + h * 64 + nt * 16 + col] = f2bits(sv[nt] * inv);
    }
  }
  // ---- Phase 4: O = P V (P rows + pa reads wave-local; V synced earlier) ----
#pragma unroll
  for (int h = 0; h < NHH; ++h) {
    floatx4 oa[2];
    oa[0] = (floatx4){0.f, 0.f, 0.f, 0.f};
    oa[1] = (floatx4){0.f, 0.f, 0.f, 0.f};
#pragma unroll
    for (int kc = 0; kc < 2; ++kc) {
      short8 pa = *(const short8*)(qk + (wave * 16 + col) * QKS + h * 64 + kc * 32 + kg * 8);
#pragma unroll
      for (int dt = 0; dt < 2; ++dt) {
        short8 vb = *(const short8*)(R + (h * HDIM + dt * 16 + col) * VTS + kc * 32 + kg * 8);
        oa[dt] = __builtin_amdgcn_mfma_f32_16x16x32_bf16(pa, vb, oa[dt], 0, 0, 0);
      }
    }
#pragma unroll
    for (int dt = 0; dt < 2; ++dt)
#pragma unroll
      for (int r = 0; r < 4; ++r) {
        int m = wave * 16 + kg * 4 + r;
        if (m < NTOK)
          attn_out[((long)win * NTOK + m) * CC + h * HDIM + dt * 16 + col] =
              f2bf(oa[dt][r]);
      }
  }
}
__global__ __launch_bounds__(256, 4) void qkv_attn_kernel(
    const int* __restrict__ flag, const void* x, const bf16* __restrict__ wq,
    const float* __restrict__ bias, const bf16* __restrict__ comb,
    bf16* __restrict__ attn_out) {
  __shared__ short qk[64 * QKS];
  __shared__ short R[6656];
  if (*flag)
    qkv_attn_body<float>((const float*)x, wq, bias, comb, attn_out, qk, R);
  else
    qkv_attn_body<bf16>((const bf16*)x, wq, bias, comb, attn_out, qk, R);
}

// ---------------------------------------------------------------------------
// window reverse + reverse shift index for token m (window order) -> image
// ---------------------------------------------------------------------------
static __device__ __forceinline__ long scatter_index(long m) {
  int win = (int)(m / NTOK);
  int n = (int)(m - (long)win * NTOK);
  int bq = win >> 8, wi = win & 255;
  int wh = wi >> 4, ww = wi & 15;
  int i = n / WSZ, j = n - (n / WSZ) * WSZ;
  int hf = wh * WSZ + i + SHIFT_; if (hf >= HH) hf -= HH;
  int wf = ww * WSZ + j + SHIFT_; if (wf >= WW_) wf -= WW_;
  return ((long)bq * (HH * WW_) + (long)hf * WW_ + wf) * CC;
}

// ---------------------------------------------------------------------------
// Proj GEMM (96x96, W frags direct from prepped bf16 cache) + scatter +
// shortcut add. Zero LDS, zero barriers.
// ---------------------------------------------------------------------------
template <typename T>
__device__ __forceinline__ void proj_body(const bf16* A, const bf16* wp,
                                          const float* bias, T* out,
                                          const T* res) {
  int wave = threadIdx.x >> 6;
  int lane = threadIdx.x & 63;
  int col = lane & 15;
  int kg = lane >> 4;
  long mbase = (long)blockIdx.x * 128 + wave * 32;
  short8 a0[3], a1[3];
#pragma unroll
  for (int kc = 0; kc < 3; ++kc) {
    a0[kc] = *(const short8*)(A + (mbase + col) * CC + kc * 32 + kg * 8);
    a1[kc] = *(const short8*)(A + (mbase + 16 + col) * CC + kc * 32 + kg * 8);
  }
  long dst0[4], dst1[4];
#pragma unroll
  for (int r = 0; r < 4; ++r) {
    dst0[r] = scatter_index(mbase + kg * 4 + r);
    dst1[r] = scatter_index(mbase + 16 + kg * 4 + r);
  }
#pragma unroll
  for (int nc = 0; nc < 6; ++nc) {
    floatx4 acc0 = {0.f, 0.f, 0.f, 0.f};
    floatx4 acc1 = {0.f, 0.f, 0.f, 0.f};
#pragma unroll
    for (int kc = 0; kc < 3; ++kc) {
      short8 bfr = *(const short8*)(wp + (nc * 16 + col) * 104 + kc * 32 + kg * 8);
      acc0 = __builtin_amdgcn_mfma_f32_16x16x32_bf16(a0[kc], bfr, acc0, 0, 0, 0);
      acc1 = __builtin_amdgcn_mfma_f32_16x16x32_bf16(a1[kc], bfr, acc1, 0, 0, 0);
    }
    int cc = nc * 16 + col;
    float bb = bias[BOF_PROJ + cc];
#pragma unroll
    for (int r = 0; r < 4; ++r) {
      long p0 = dst0[r] + cc;
      long p1 = dst1[r] + cc;
      IO<T>::st(out, p0, acc0[r] + bb + IO<T>::ld(res, p0));
      IO<T>::st(out, p1, acc1[r] + bb + IO<T>::ld(res, p1));
    }
  }
}
__global__ __launch_bounds__(256, 4) void proj_kernel(
    const int* __restrict__ flag, const bf16* __restrict__ A,
    const bf16* __restrict__ wp, const float* __restrict__ bias, void* out,
    const void* res) {
  if (*flag)
    proj_body<float>(A, wp, bias, (float*)out, (const float*)res);
  else
    proj_body<bf16>(A, wp, bias, (bf16*)out, (const bf16*)res);
}

// ---------------------------------------------------------------------------
// Fused LN2 + MLP. One block = 64 rows. Weight frags direct from prepped
// cache (1 dwordx4 each). Raw x1 rows stashed in LDS (f32, stride 97) during
// the LN2 load, so the residual add reads LDS instead of re-fetching 154 MB
// from HBM (round-4 counters: FETCH 2x ideal, WRITE 4x ideal from L2 thrash
// at 8 blocks/CU). 4 blocks/CU keeps the in-flight footprint L2-resident.
// One barrier total (xln->h1c stride-alias, round-3 bug).
// LDS: xln 13312 B + xstash 24832 B = 38144 B -> 4 blocks/CU.
// ---------------------------------------------------------------------------
template <typename T>
__device__ __forceinline__ void mlp_body(const bf16* w1, const bf16* w2,
                                         const float* bias, T* xo, short* xln,
                                         float* xstash) {
  int wave = threadIdx.x >> 6;
  int lane = threadIdx.x & 63;
  int col = lane & 15;
  int kg = lane >> 4;
  long mbase = (long)blockIdx.x * 64;
  // ---- LN2 on x1 (= xo) -> xln; raw values -> xstash (both wave-local) ----
  {
    int r = lane >> 2;
    int seg = lane & 3;
    const T* src = xo + (mbase + wave * 16 + r) * CC + seg * 24;
    float a[24];
#pragma unroll
    for (int t = 0; t < 24; ++t) a[t] = IO<T>::ld(src, t);
    float* stw = xstash + (wave * 16 + r) * XSS + seg * 24;
#pragma unroll
    for (int t = 0; t < 24; ++t) stw[t] = a[t];
    float s = 0.f;
#pragma unroll
    for (int t = 0; t < 24; ++t) s += a[t];
    s += __shfl_xor(s, 1, 64);
    s += __shfl_xor(s, 2, 64);
    float mean = s * (1.f / CC);
    float var = 0.f;
#pragma unroll
    for (int t = 0; t < 24; ++t) { float d = a[t] - mean; var += d * d; }
    var += __shfl_xor(var, 1, 64);
    var += __shfl_xor(var, 2, 64);
    float rstd = rsqrtf(var * (1.f / CC) + 1e-5f);
    const float* gg = bias + BOF_G2 + seg * 24;
    const float* bb = bias + BOF_B2 + seg * 24;
    short* dst = xln + (wave * 16 + r) * 104 + seg * 24;
#pragma unroll
    for (int t = 0; t < 24; ++t)
      dst[t] = f2bits((a[t] - mean) * rstd * gg[t] + bb[t]);
  }
  // af reads this wave's own xln rows -> in-wave ordering, no barrier needed
  short8 af[3];
#pragma unroll
  for (int kc = 0; kc < 3; ++kc)
    af[kc] = *(const short8*)(xln + (wave * 16 + col) * 104 + kc * 32 + kg * 8);
  __syncthreads();  // ALL waves' af loaded before h1c overlay (stride alias!)
  short* h1c = xln;  // xln dead now -> reuse as h1 chunk (stride H1S)
  floatx4 acc2[6];
#pragma unroll
  for (int i = 0; i < 6; ++i) acc2[i] = (floatx4){0.f, 0.f, 0.f, 0.f};
  for (int c = 0; c < 6; ++c) {
    // FC1 chunk: 4 n-tiles -> gelu -> h1c (wave-local rows)
#pragma unroll
    for (int t = 0; t < 4; ++t) {
      floatx4 acc = {0.f, 0.f, 0.f, 0.f};
#pragma unroll
      for (int kc = 0; kc < 3; ++kc) {
        short8 bfr =
            *(const short8*)(w1 + (c * 64 + t * 16 + col) * 104 + kc * 32 + kg * 8);
        acc = __builtin_amdgcn_mfma_f32_16x16x32_bf16(af[kc], bfr, acc, 0, 0, 0);
      }
      float bb = bias[BOF_FC1 + c * 64 + t * 16 + col];
#pragma unroll
      for (int r = 0; r < 4; ++r) {
        float v = acc[r] + bb;
        float ge = 0.5f * v * (1.f + erff(v * 0.70710678118654752f));
        h1c[(wave * 16 + kg * 4 + r) * H1S + t * 16 + col] = f2bits(ge);
      }
    }
    // FC2 partial (h1c rows wave-local -> in-wave ordering, no barrier)
    short8 a2[2];
#pragma unroll
    for (int kk = 0; kk < 2; ++kk)
      a2[kk] = *(const short8*)(h1c + (wave * 16 + col) * H1S + kk * 32 + kg * 8);
#pragma unroll
    for (int nc2 = 0; nc2 < 6; ++nc2) {
#pragma unroll
      for (int kk = 0; kk < 2; ++kk) {
        short8 b2f = *(const short8*)(w2 + c * (96 * 72) + (nc2 * 16 + col) * 72 +
                                      kk * 32 + kg * 8);
        acc2[nc2] = __builtin_amdgcn_mfma_f32_16x16x32_bf16(a2[kk], b2f, acc2[nc2], 0, 0, 0);
      }
    }
  }
  // ---- epilogue: + fc2_b + residual (from LDS stash), write back ----
#pragma unroll
  for (int nc2 = 0; nc2 < 6; ++nc2) {
    int cc = nc2 * 16 + col;
    float bb = bias[BOF_FC2 + cc];
#pragma unroll
    for (int r = 0; r < 4; ++r) {
      int row = wave * 16 + kg * 4 + r;
      float resv = xstash[row * XSS + cc];
      long p = (mbase + row) * CC + cc;
      IO<T>::st(xo, p, acc2[nc2][r] + bb + resv);
    }
  }
}
__global__ __launch_bounds__(256, 4) void mlp_kernel(
    const int* __restrict__ flag, const bf16* __restrict__ w1,
    const bf16* __restrict__ w2, const float* __restrict__ bias, void* xo) {
  __shared__ short xln[64 * 104];
  __shared__ float xstash[64 * XSS];
  if (*flag)
    mlp_body<float>(w1, w2, bias, (float*)xo, xln, xstash);
  else
    mlp_body<bf16>(w1, w2, bias, (bf16*)xo, xln, xstash);
}

// ---------------------------------------------------------------------------
extern "C" void kernel_launch(void* const* d_in, const int* in_sizes, int n_in,
                              void* d_out, int out_size, void* d_ws, size_t ws_size,
                              hipStream_t stream) {
  (void)in_sizes; (void)n_in; (void)out_size; (void)ws_size;
  char* ws = (char*)d_ws;
  bf16* bufA = (bf16*)ws;                                   // MTOT*96 bf16 = 77 MB
  size_t offComb = (size_t)MTOT * CC * 2;
  bf16* comb = (bf16*)(ws + offComb);                       // 256*3*2401 bf16 = 3.7 MB
  size_t offW = offComb + (size_t)256 * NHH * 2401 * 2;
  bf16* wpad = (bf16*)(ws + offW);                          // 237 KB padded bf16 weights
  size_t offB = offW + (size_t)WPAD_TOT * 2;
  float* bias = (float*)(ws + offB);                        // 4.9 KB f32 biases/params
  int* flag = (int*)(ws + offB + (size_t)BIAS_TOT * 4);

  detect_kernel<<<1, 256, 0, stream>>>((const unsigned short*)d_in[0], flag);
  prep_kernel<<<(WPAD_TOT + BIAS_TOT + 255) / 256, 256, 0, stream>>>(
      flag, d_in[5], d_in[7], d_in[12], d_in[14], d_in[6], d_in[8], d_in[13],
      d_in[15], d_in[3], d_in[4], d_in[10], d_in[11], wpad, bias);
  combine_kernel<<<7203, 256, 0, stream>>>(flag, d_in[1], (const int*)d_in[2],
                                           d_in[9], comb);
  // 1. LN1 + shift + QKV + attention -> bufA
  qkv_attn_kernel<<<WTOT, 256, 0, stream>>>(flag, d_in[0], wpad, bias, comb, bufA);
  // 2. proj + scatter + shortcut -> x1 parked in d_out
  proj_kernel<<<MTOT / 128, 256, 0, stream>>>(flag, bufA, wpad + WQ_SZ, bias,
                                              d_out, d_in[0]);
  // 3. LN2 + MLP + residual, in-place on d_out
  mlp_kernel<<<MTOT / 64, 256, 0, stream>>>(flag, wpad + WQ_SZ + WP_SZ,
                                            wpad + WQ_SZ + WP_SZ + W1_SZ, bias,
                                            d_out);
}

// Round 6
// 781.034 us; speedup vs baseline: 1.3345x; 1.1043x over previous
//
#include <hip/hip_runtime.h>
#include <hip/hip_bf16.h>
#include <math.h>

#define HH 112
#define WW_ 112
#define CC 96
#define NHH 3
#define WSZ 7
#define SHIFT_ 3
#define NTOK 49
#define HDIM 32
#define WTOT 8192          // total windows = B * 16 * 16
#define MTOT 401408        // WTOT * NTOK
#define QKS 204            // qk LDS row stride (shorts): 102 dwords === 6 (mod 32)
#define H1S 76             // h1 LDS row stride (shorts): 38 dwords === 6 (mod 32)
#define VTS 68             // vT row stride (shorts)

// ---- padded bf16 weight cache layout in workspace (shorts) ----
#define WQ_SZ (288 * 104)              // qkv_w rows, stride 104
#define WP_SZ (96 * 104)               // proj_w rows, stride 104
#define W1_SZ (384 * 104)              // fc1_w rows, stride 104
#define W2_SZ (6 * 96 * 72)            // fc2_w: 6 chunks of [96][72] (64 used + pad)
#define WPAD_TOT (WQ_SZ + WP_SZ + W1_SZ + W2_SZ)  // 121344
// ---- float bias/param cache offsets ----
#define BOF_QKV 0
#define BOF_PROJ 288
#define BOF_FC1 384
#define BOF_FC2 768
#define BOF_G1 864
#define BOF_B1 960
#define BOF_G2 1056
#define BOF_B2 1152
#define BIAS_TOT 1248

typedef __hip_bfloat16 bf16;
typedef __attribute__((ext_vector_type(8))) short short8;
typedef __attribute__((ext_vector_type(4))) float floatx4;

static __device__ __forceinline__ float bits2f(short s) {
  return __uint_as_float(((unsigned)(unsigned short)s) << 16);
}
static __device__ __forceinline__ short f2bits(float v) {
  bf16 h = __float2bfloat16(v);
  short s;
  __builtin_memcpy(&s, &h, 2);
  return s;
}
static __device__ __forceinline__ float bf2f(bf16 v) { return __bfloat162float(v); }
static __device__ __forceinline__ bf16 f2bf(float v) { return __float2bfloat16(v); }

template <typename T> struct IO;
template <> struct IO<float> {
  static __device__ __forceinline__ float ld(const float* p, long i) { return p[i]; }
  static __device__ __forceinline__ void st(float* p, long i, float v) { p[i] = v; }
  static __device__ __forceinline__ void ld24(float* a, const float* p) {
    const float4* q = (const float4*)p;  // 96B-offset aligned -> 16B ok
#pragma unroll
    for (int i = 0; i < 6; ++i) {
      float4 v = q[i];
      a[4 * i] = v.x; a[4 * i + 1] = v.y; a[4 * i + 2] = v.z; a[4 * i + 3] = v.w;
    }
  }
};
template <> struct IO<bf16> {
  static __device__ __forceinline__ float ld(const bf16* p, long i) { return bf2f(p[i]); }
  static __device__ __forceinline__ void st(bf16* p, long i, float v) { p[i] = f2bf(v); }
  static __device__ __forceinline__ void ld24(float* a, const bf16* p) {
    const short8* q = (const short8*)p;  // 48B-offset aligned -> 16B ok
#pragma unroll
    for (int i = 0; i < 3; ++i) {
      short8 v = q[i];
#pragma unroll
      for (int j = 0; j < 8; ++j) a[8 * i + j] = bits2f(v[j]);
    }
  }
};

// ---------------------------------------------------------------------------
// dtype detection: flag = 1 if input is f32, 0 if bf16.
// ---------------------------------------------------------------------------
__global__ void detect_kernel(const unsigned short* __restrict__ x, int* flag) {
  __shared__ int tot;
  if (threadIdx.x == 0) tot = 0;
  __syncthreads();
  int bad = 0;
  for (int i = threadIdx.x; i < 8192; i += 256) {
    int e = (x[i] >> 7) & 0xFF;
    if (e >= 0x86) bad++;  // |value| >= 128 (or inf/nan)
  }
  atomicAdd(&tot, bad);
  __syncthreads();
  if (threadIdx.x == 0) *flag = (tot > 64) ? 1 : 0;
}

// ---------------------------------------------------------------------------
// One-time prep: weights -> bf16 padded fragment layouts; biases/LN -> f32.
// ---------------------------------------------------------------------------
template <typename T>
__device__ __forceinline__ void prep_body(
    const T* qkv_w, const T* proj_w, const T* fc1_w, const T* fc2_w,
    const T* qkv_b, const T* proj_b, const T* fc1_b, const T* fc2_b,
    const T* g1, const T* b1, const T* g2, const T* b2,
    bf16* wpad, float* bias) {
  int idx = blockIdx.x * 256 + threadIdx.x;
  if (idx < WQ_SZ) {
    int r = idx / 104, c = idx % 104;
    wpad[idx] = (c < CC) ? f2bf(IO<T>::ld(qkv_w, (long)r * CC + c)) : f2bf(0.f);
  } else if (idx < WQ_SZ + WP_SZ) {
    int j = idx - WQ_SZ;
    int r = j / 104, c = j % 104;
    wpad[idx] = (c < CC) ? f2bf(IO<T>::ld(proj_w, (long)r * CC + c)) : f2bf(0.f);
  } else if (idx < WQ_SZ + WP_SZ + W1_SZ) {
    int j = idx - (WQ_SZ + WP_SZ);
    int r = j / 104, c = j % 104;
    wpad[idx] = (c < CC) ? f2bf(IO<T>::ld(fc1_w, (long)r * CC + c)) : f2bf(0.f);
  } else if (idx < WPAD_TOT) {
    int j = idx - (WQ_SZ + WP_SZ + W1_SZ);
    int ch = j / (96 * 72), rem = j % (96 * 72);
    int r = rem / 72, c = rem % 72;
    wpad[idx] = (c < 64) ? f2bf(IO<T>::ld(fc2_w, (long)r * (4 * CC) + ch * 64 + c))
                         : f2bf(0.f);
  } else if (idx < WPAD_TOT + BIAS_TOT) {
    int j = idx - WPAD_TOT;
    float v;
    if (j < 288) v = IO<T>::ld(qkv_b, j);
    else if (j < 384) v = IO<T>::ld(proj_b, j - 288);
    else if (j < 768) v = IO<T>::ld(fc1_b, j - 384);
    else if (j < 864) v = IO<T>::ld(fc2_b, j - 768);
    else if (j < 960) v = IO<T>::ld(g1, j - 864);
    else if (j < 1056) v = IO<T>::ld(b1, j - 960);
    else if (j < 1152) v = IO<T>::ld(g2, j - 1056);
    else v = IO<T>::ld(b2, j - 1152);
    bias[j] = v;
  }
}
__global__ __launch_bounds__(256) void prep_kernel(
    const int* __restrict__ flag, const void* qkv_w, const void* proj_w,
    const void* fc1_w, const void* fc2_w, const void* qkv_b, const void* proj_b,
    const void* fc1_b, const void* fc2_b, const void* g1, const void* b1,
    const void* g2, const void* b2, bf16* __restrict__ wpad,
    float* __restrict__ bias) {
  if (*flag)
    prep_body<float>((const float*)qkv_w, (const float*)proj_w, (const float*)fc1_w,
                     (const float*)fc2_w, (const float*)qkv_b, (const float*)proj_b,
                     (const float*)fc1_b, (const float*)fc2_b, (const float*)g1,
                     (const float*)b1, (const float*)g2, (const float*)b2, wpad, bias);
  else
    prep_body<bf16>((const bf16*)qkv_w, (const bf16*)proj_w, (const bf16*)fc1_w,
                    (const bf16*)fc2_w, (const bf16*)qkv_b, (const bf16*)proj_b,
                    (const bf16*)fc1_b, (const bf16*)fc2_b, (const bf16*)g1,
                    (const bf16*)b1, (const bf16*)g2, (const bf16*)b2, wpad, bias);
}

// ---------------------------------------------------------------------------
// Combined bias+mask table: comb[wi][h][m][n] (bf16)
// ---------------------------------------------------------------------------
template <typename T>
__device__ __forceinline__ void combine_body(const T* mask, const int* rel,
                                             const T* bt, bf16* comb) {
  long idx = (long)blockIdx.x * 256 + threadIdx.x;  // [wi][h][2401]
  long rem = idx % 7203;
  long wi = idx / 7203;
  int h = (int)(rem / 2401);
  int n2 = (int)(rem % 2401);
  float v = IO<T>::ld(bt, (long)rel[n2] * NHH + h) + IO<T>::ld(mask, wi * 2401 + n2);
  comb[idx] = f2bf(v);
}
__global__ __launch_bounds__(256) void combine_kernel(
    const int* __restrict__ flag, const void* mask, const int* __restrict__ rel,
    const void* bt, bf16* __restrict__ comb) {
  if (*flag)
    combine_body<float>((const float*)mask, rel, (const float*)bt, comb);
  else
    combine_body<bf16>((const bf16*)mask, rel, (const bf16*)bt, comb);
}

// ---------------------------------------------------------------------------
// FULLY FUSED Swin block: LN1 + QKV + window attention + proj + residual +
// LN2 + MLP + residual, one block per window. x read once, out written once.
// LDS regions:
//   qk [64][QKS] : Q(0..95 prescaled) | K(96..191) -> P overlay -> O overlay
//                  -> h1c overlay (stride 76, after barrier 4)
//   R  [6656]    : xln (stride 104) -> vT (stride 68) -> xln2 (stride 104)
//   xst[64][104] : raw x rows (bf16) -> x1 rows in place
// 52736 B -> 3 blocks/CU. 4 barriers total.
// ---------------------------------------------------------------------------
template <typename T>
__device__ __forceinline__ void fused_body(
    const T* x, const bf16* wq, const bf16* wp, const bf16* w1, const bf16* w2,
    const float* bias, const bf16* comb, T* out, short* qk, short* R,
    short* xst) {
  int win = blockIdx.x;
  int wave = threadIdx.x >> 6;
  int lane = threadIdx.x & 63;
  int col = lane & 15, kg = lane >> 4;
  int bq_ = win >> 8, wi = win & 255;
  int wh = wi >> 4, ww = wi & 15;
  // ---- LN1 + cyclic-shift gather -> xln (R); raw x -> xst (wave-local) ----
  {
    int r = lane >> 2;
    int seg = lane & 3;
    int n = wave * 16 + r;  // token in window (0..63)
    short* dst = R + n * 104 + seg * 24;
    short* stw = xst + n * 104 + seg * 24;
    if (n < NTOK) {
      int i = n / WSZ, j = n - (n / WSZ) * WSZ;
      int hs = wh * WSZ + i + SHIFT_; if (hs >= HH) hs -= HH;
      int ws = ww * WSZ + j + SHIFT_; if (ws >= WW_) ws -= WW_;
      const T* src = x + ((long)bq_ * (HH * WW_) + (long)hs * WW_ + ws) * CC + seg * 24;
      float a[24];
      IO<T>::ld24(a, src);
      float s = 0.f;
#pragma unroll
      for (int t = 0; t < 24; ++t) s += a[t];
      s += __shfl_xor(s, 1, 64);
      s += __shfl_xor(s, 2, 64);
      float mean = s * (1.f / CC);
      float var = 0.f;
#pragma unroll
      for (int t = 0; t < 24; ++t) { float d = a[t] - mean; var += d * d; }
      var += __shfl_xor(var, 1, 64);
      var += __shfl_xor(var, 2, 64);
      float rstd = rsqrtf(var * (1.f / CC) + 1e-5f);
      const float* gg = bias + BOF_G1 + seg * 24;
      const float* bb = bias + BOF_B1 + seg * 24;
#pragma unroll
      for (int t = 0; t < 24; ++t) {
        stw[t] = f2bits(a[t]);
        dst[t] = f2bits((a[t] - mean) * rstd * gg[t] + bb[t]);
      }
    } else {
#pragma unroll
      for (int t = 0; t < 24; ++t) { dst[t] = 0; stw[t] = 0; }
    }
  }
  // af reads only this wave's xln rows -> in-wave DS ordering, no barrier.
  short8 af[3];
#pragma unroll
  for (int kc = 0; kc < 3; ++kc)
    af[kc] = *(const short8*)(R + (wave * 16 + col) * 104 + kc * 32 + kg * 8);
  const float scale = 0.17677669529663687f;  // 1/sqrt(32)
  // ---- Phase 1a: Q,K tiles (nc 0..11), B-frags direct from L2 cache ----
#pragma unroll
  for (int nc = 0; nc < 12; ++nc) {
    floatx4 acc = {0.f, 0.f, 0.f, 0.f};
#pragma unroll
    for (int kc = 0; kc < 3; ++kc) {
      short8 bfr = *(const short8*)(wq + (nc * 16 + col) * 104 + kc * 32 + kg * 8);
      acc = __builtin_amdgcn_mfma_f32_16x16x32_bf16(af[kc], bfr, acc, 0, 0, 0);
    }
    int cc = nc * 16 + col;
    float bb = bias[BOF_QKV + cc];
    float m = (nc < 6) ? scale : 1.f;  // prescale Q
#pragma unroll
    for (int r = 0; r < 4; ++r)
      qk[(wave * 16 + kg * 4 + r) * QKS + cc] = f2bits((acc[r] + bb) * m);
  }
  __syncthreads();  // barrier 1: all waves' af consumed -> xln reusable as vT
  // ---- Phase 1b: V tiles (nc 12..17) -> transposed vT[d][token] in R ----
#pragma unroll
  for (int nc = 12; nc < 18; ++nc) {
    floatx4 acc = {0.f, 0.f, 0.f, 0.f};
#pragma unroll
    for (int kc = 0; kc < 3; ++kc) {
      short8 bfr = *(const short8*)(wq + (nc * 16 + col) * 104 + kc * 32 + kg * 8);
      acc = __builtin_amdgcn_mfma_f32_16x16x32_bf16(af[kc], bfr, acc, 0, 0, 0);
    }
    int cc = nc * 16 + col;
    float bb = bias[BOF_QKV + cc];
    int d = cc - 2 * CC;
#pragma unroll
    for (int r = 0; r < 4; ++r)
      R[d * VTS + wave * 16 + kg * 4 + r] = f2bits(acc[r] + bb);
  }
  __syncthreads();  // barrier 2: K,V visible to all waves
  // ---- Phase 2: S = Q K^T (registers) ----
  floatx4 st[3][4];
#pragma unroll
  for (int h = 0; h < NHH; ++h) {
    short8 qa = *(const short8*)(qk + (wave * 16 + col) * QKS + h * HDIM + kg * 8);
#pragma unroll
    for (int nt = 0; nt < 4; ++nt) {
      short8 kb = *(const short8*)(qk + (nt * 16 + col) * QKS + CC + h * HDIM + kg * 8);
      floatx4 z = {0.f, 0.f, 0.f, 0.f};
      st[h][nt] = __builtin_amdgcn_mfma_f32_16x16x32_bf16(qa, kb, z, 0, 0, 0);
    }
  }
  __syncthreads();  // barrier 3: Q,K region dead -> P overlay safe
  // ---- Phase 3: softmax -> P overlay into qk cols 0..191 (own rows) ----
  const bf16* cb = comb + (long)wi * (NHH * 2401);
#pragma unroll
  for (int h = 0; h < NHH; ++h) {
#pragma unroll
    for (int r = 0; r < 4; ++r) {
      int m = wave * 16 + kg * 4 + r;
      int mc = (m < NTOK) ? m : (NTOK - 1);
      float sv[4];
      float mx = -1e30f;
#pragma unroll
      for (int nt = 0; nt < 4; ++nt) {
        int n = nt * 16 + col;
        float v = (n < NTOK)
                      ? (st[h][nt][r] + bf2f(cb[h * 2401 + mc * NTOK + n]))
                      : -1e30f;
        sv[nt] = v;
        mx = fmaxf(mx, v);
      }
#pragma unroll
      for (int msk = 1; msk < 16; msk <<= 1) mx = fmaxf(mx, __shfl_xor(mx, msk, 64));
      float sum = 0.f;
#pragma unroll
      for (int nt = 0; nt < 4; ++nt) {
        float e = __expf(sv[nt] - mx);
        sv[nt] = e;
        sum += e;
      }
#pragma unroll
      for (int msk = 1; msk < 16; msk <<= 1) sum += __shfl_xor(sum, msk, 64);
      float inv = 1.f / sum;
#pragma unroll
      for (int nt = 0; nt < 4; ++nt)
        qk[m * QKS + h * 64 + nt * 16 + col] = f2bits(sv[nt] * inv);
    }
  }
  // ---- Phase 4: O = P V; O overlays qk cols h*32.. of OWN rows.
  //      Safe per-h: O cols [32h,32h+31] only overlap P of heads < h. ----
#pragma unroll
  for (int h = 0; h < NHH; ++h) {
    floatx4 oa[2];
    oa[0] = (floatx4){0.f, 0.f, 0.f, 0.f};
    oa[1] = (floatx4){0.f, 0.f, 0.f, 0.f};
#pragma unroll
    for (int kc = 0; kc < 2; ++kc) {
      short8 pa = *(const short8*)(qk + (wave * 16 + col) * QKS + h * 64 + kc * 32 + kg * 8);
#pragma unroll
      for (int dt = 0; dt < 2; ++dt) {
        short8 vb = *(const short8*)(R + (h * HDIM + dt * 16 + col) * VTS + kc * 32 + kg * 8);
        oa[dt] = __builtin_amdgcn_mfma_f32_16x16x32_bf16(pa, vb, oa[dt], 0, 0, 0);
      }
    }
#pragma unroll
    for (int dt = 0; dt < 2; ++dt)
#pragma unroll
      for (int r = 0; r < 4; ++r)
        qk[(wave * 16 + kg * 4 + r) * QKS + h * 32 + dt * 16 + col] =
            f2bits(oa[dt][r]);
  }
  // ---- proj (in-block): A-frags from O (own rows, in-wave RAW) ----
  short8 pf[3];
#pragma unroll
  for (int kc = 0; kc < 3; ++kc)
    pf[kc] = *(const short8*)(qk + (wave * 16 + col) * QKS + kc * 32 + kg * 8);
  float x1v[6][4];
#pragma unroll
  for (int nc = 0; nc < 6; ++nc) {
    floatx4 acc = {0.f, 0.f, 0.f, 0.f};
#pragma unroll
    for (int kc = 0; kc < 3; ++kc) {
      short8 bfr = *(const short8*)(wp + (nc * 16 + col) * 104 + kc * 32 + kg * 8);
      acc = __builtin_amdgcn_mfma_f32_16x16x32_bf16(pf[kc], bfr, acc, 0, 0, 0);
    }
    int cc = nc * 16 + col;
    float bb = bias[BOF_PROJ + cc];
#pragma unroll
    for (int r = 0; r < 4; ++r) {
      int row = wave * 16 + kg * 4 + r;
      x1v[nc][r] = acc[r] + bb + bits2f(xst[row * 104 + cc]);
    }
  }
  // x1 -> xst in place (own rows; rows >= NTOK hold junk x1, never read back)
#pragma unroll
  for (int nc = 0; nc < 6; ++nc)
#pragma unroll
    for (int r = 0; r < 4; ++r)
      xst[(wave * 16 + kg * 4 + r) * 104 + nc * 16 + col] = f2bits(x1v[nc][r]);
  __syncthreads();  // barrier 4: all PV vT-reads + proj O-reads done ->
                    // R reusable as xln2, qk reusable as h1c
  // ---- LN2 on x1 (registers) -> xln2 in R (stride 104) ----
#pragma unroll
  for (int r = 0; r < 4; ++r) {
    int row = wave * 16 + kg * 4 + r;
    float s = 0.f;
#pragma unroll
    for (int nc = 0; nc < 6; ++nc) s += x1v[nc][r];
#pragma unroll
    for (int msk = 1; msk < 16; msk <<= 1) s += __shfl_xor(s, msk, 64);
    float mean = s * (1.f / CC);
    float var = 0.f;
#pragma unroll
    for (int nc = 0; nc < 6; ++nc) { float d = x1v[nc][r] - mean; var += d * d; }
#pragma unroll
    for (int msk = 1; msk < 16; msk <<= 1) var += __shfl_xor(var, msk, 64);
    float rstd = rsqrtf(var * (1.f / CC) + 1e-5f);
    bool live = (row < NTOK);
#pragma unroll
    for (int nc = 0; nc < 6; ++nc) {
      int cc = nc * 16 + col;
      float v = live ? ((x1v[nc][r] - mean) * rstd * bias[BOF_G2 + cc] +
                        bias[BOF_B2 + cc])
                     : 0.f;
      R[row * 104 + cc] = f2bits(v);
    }
  }
  // am reads this wave's own xln2 rows -> in-wave ordering, no barrier
  short8 am[3];
#pragma unroll
  for (int kc = 0; kc < 3; ++kc)
    am[kc] = *(const short8*)(R + (wave * 16 + col) * 104 + kc * 32 + kg * 8);
  short* h1c = qk;  // qk dead -> h1 chunk (stride H1S, wave-local both sides)
  floatx4 acc2[6];
#pragma unroll
  for (int i = 0; i < 6; ++i) acc2[i] = (floatx4){0.f, 0.f, 0.f, 0.f};
  for (int c = 0; c < 6; ++c) {
    // FC1 chunk: 4 n-tiles -> gelu -> h1c
#pragma unroll
    for (int t = 0; t < 4; ++t) {
      floatx4 acc = {0.f, 0.f, 0.f, 0.f};
#pragma unroll
      for (int kc = 0; kc < 3; ++kc) {
        short8 bfr =
            *(const short8*)(w1 + (c * 64 + t * 16 + col) * 104 + kc * 32 + kg * 8);
        acc = __builtin_amdgcn_mfma_f32_16x16x32_bf16(am[kc], bfr, acc, 0, 0, 0);
      }
      float bb = bias[BOF_FC1 + c * 64 + t * 16 + col];
#pragma unroll
      for (int r = 0; r < 4; ++r) {
        float v = acc[r] + bb;
        float ge = 0.5f * v * (1.f + erff(v * 0.70710678118654752f));
        h1c[(wave * 16 + kg * 4 + r) * H1S + t * 16 + col] = f2bits(ge);
      }
    }
    // FC2 partial (own rows, in-wave ordering)
    short8 a2[2];
#pragma unroll
    for (int kk = 0; kk < 2; ++kk)
      a2[kk] = *(const short8*)(h1c + (wave * 16 + col) * H1S + kk * 32 + kg * 8);
#pragma unroll
    for (int nc2 = 0; nc2 < 6; ++nc2) {
#pragma unroll
      for (int kk = 0; kk < 2; ++kk) {
        short8 b2f = *(const short8*)(w2 + c * (96 * 72) + (nc2 * 16 + col) * 72 +
                                      kk * 32 + kg * 8);
        acc2[nc2] = __builtin_amdgcn_mfma_f32_16x16x32_bf16(a2[kk], b2f, acc2[nc2], 0, 0, 0);
      }
    }
  }
  // ---- final epilogue: out[scatter] = y + fc2_b + x1 (from xst) ----
  long dst[4];
  bool liv[4];
#pragma unroll
  for (int r = 0; r < 4; ++r) {
    int n = wave * 16 + kg * 4 + r;
    liv[r] = (n < NTOK);
    if (liv[r]) {
      int i = n / WSZ, j = n - (n / WSZ) * WSZ;
      int hf = wh * WSZ + i + SHIFT_; if (hf >= HH) hf -= HH;
      int wf = ww * WSZ + j + SHIFT_; if (wf >= WW_) wf -= WW_;
      dst[r] = ((long)bq_ * (HH * WW_) + (long)hf * WW_ + wf) * CC;
    } else {
      dst[r] = 0;
    }
  }
#pragma unroll
  for (int nc2 = 0; nc2 < 6; ++nc2) {
    int cc = nc2 * 16 + col;
    float bb = bias[BOF_FC2 + cc];
#pragma unroll
    for (int r = 0; r < 4; ++r) {
      if (liv[r]) {
        int row = wave * 16 + kg * 4 + r;
        float resv = bits2f(xst[row * 104 + cc]);
        IO<T>::st(out, dst[r] + cc, acc2[nc2][r] + bb + resv);
      }
    }
  }
}
__global__ __launch_bounds__(256, 3) void fused_kernel(
    const int* __restrict__ flag, const void* x, const bf16* __restrict__ wq,
    const bf16* __restrict__ wp, const bf16* __restrict__ w1,
    const bf16* __restrict__ w2, const float* __restrict__ bias,
    const bf16* __restrict__ comb, void* out) {
  __shared__ short qk[64 * QKS];
  __shared__ short R[6656];
  __shared__ short xst[64 * 104];
  if (*flag)
    fused_body<float>((const float*)x, wq, wp, w1, w2, bias, comb, (float*)out,
                      qk, R, xst);
  else
    fused_body<bf16>((const bf16*)x, wq, wp, w1, w2, bias, comb, (bf16*)out,
                     qk, R, xst);
}

// ---------------------------------------------------------------------------
extern "C" void kernel_launch(void* const* d_in, const int* in_sizes, int n_in,
                              void* d_out, int out_size, void* d_ws, size_t ws_size,
                              hipStream_t stream) {
  (void)in_sizes; (void)n_in; (void)out_size; (void)ws_size;
  char* ws = (char*)d_ws;
  bf16* comb = (bf16*)ws;                                   // 256*3*2401 bf16 = 3.7 MB
  size_t offW = (size_t)256 * NHH * 2401 * 2;
  bf16* wpad = (bf16*)(ws + offW);                          // 237 KB padded bf16 weights
  size_t offB = offW + (size_t)WPAD_TOT * 2;
  float* bias = (float*)(ws + offB);                        // 4.9 KB f32 biases/params
  int* flag = (int*)(ws + offB + (size_t)BIAS_TOT * 4);

  detect_kernel<<<1, 256, 0, stream>>>((const unsigned short*)d_in[0], flag);
  prep_kernel<<<(WPAD_TOT + BIAS_TOT + 255) / 256, 256, 0, stream>>>(
      flag, d_in[5], d_in[7], d_in[12], d_in[14], d_in[6], d_in[8], d_in[13],
      d_in[15], d_in[3], d_in[4], d_in[10], d_in[11], wpad, bias);
  combine_kernel<<<7203, 256, 0, stream>>>(flag, d_in[1], (const int*)d_in[2],
                                           d_in[9], comb);
  // One fused kernel: LN1+QKV+attn+proj+residual+LN2+MLP+residual per window.
  fused_kernel<<<WTOT, 256, 0, stream>>>(flag, d_in[0], wpad, wpad + WQ_SZ,
                                         wpad + WQ_SZ + WP_SZ,
                                         wpad + WQ_SZ + WP_SZ + W1_SZ, bias,
                                         comb, d_out);
}